// Round 4
// baseline (66.250 us; speedup 1.0000x reference)
//
#include <hip/hip_runtime.h>

// OptimalTrajLoss: B=16384 structures x 64 atoms, 27 periodic images.
// R4: init-kernel (zero out) -> main kernel with per-wave float atomicAdd.
// No reduce kernel, no memset node (R2: fillBuffer dispatch ~40us).

static constexpr int BSTRUCT = 16384;
static constexpr int NATOMS  = BSTRUCT * 64;            // 1048576
static constexpr int BLOCK   = 256;
static constexpr int APT     = 4;                       // atoms per thread
static constexpr int GRID    = NATOMS / (BLOCK * APT);  // 1024
static constexpr float INV3N = 1.0f / (3.0f * (float)NATOMS);

__global__ void otl_init(float* __restrict__ out) {
    if (threadIdx.x == 0) out[0] = 0.0f;
}

__global__ __launch_bounds__(BLOCK) void otl_main(
    const float* __restrict__ cell,
    const float* __restrict__ x,
    const float* __restrict__ xt,
    const float* __restrict__ xtr,
    float* __restrict__ out)
{
    const int t = threadIdx.x;

    // Stage this block's 16 structures' cells (16*9 floats) through LDS.
    __shared__ float cl[16 * 9];
    if (t < 144) cl[t] = cell[blockIdx.x * 144 + t];
    __syncthreads();

    // Cell for this thread's structure (16 consecutive lanes share).
    const float* c = &cl[(t >> 4) * 9];
    const float c00 = c[0], c01 = c[1], c02 = c[2];
    const float c10 = c[3], c11 = c[4], c12 = c[5];
    const float c20 = c[6], c21 = c[7], c22 = c[8];

    // 4 atoms = 12 floats = 3 float4 per array, coalesced dwordx4.
    const int f4 = (blockIdx.x * BLOCK + t) * 3;
    const float4 xa = reinterpret_cast<const float4*>(x)[f4 + 0];
    const float4 xb = reinterpret_cast<const float4*>(x)[f4 + 1];
    const float4 xc = reinterpret_cast<const float4*>(x)[f4 + 2];
    const float4 ta = reinterpret_cast<const float4*>(xt)[f4 + 0];
    const float4 tb = reinterpret_cast<const float4*>(xt)[f4 + 1];
    const float4 tc = reinterpret_cast<const float4*>(xt)[f4 + 2];
    const float4 ja = reinterpret_cast<const float4*>(xtr)[f4 + 0];
    const float4 jb = reinterpret_cast<const float4*>(xtr)[f4 + 1];
    const float4 jc = reinterpret_cast<const float4*>(xtr)[f4 + 2];

    float dx[APT], dy[APT], dz[APT];      // x_tilde - x
    {
        const float X[12] = {xa.x,xa.y,xa.z,xa.w,xb.x,xb.y,xb.z,xb.w,xc.x,xc.y,xc.z,xc.w};
        const float T[12] = {ta.x,ta.y,ta.z,ta.w,tb.x,tb.y,tb.z,tb.w,tc.x,tc.y,tc.z,tc.w};
        #pragma unroll
        for (int k = 0; k < APT; ++k) {
            dx[k] = T[k*3+0] - X[k*3+0];
            dy[k] = T[k*3+1] - X[k*3+1];
            dz[k] = T[k*3+2] - X[k*3+2];
        }
    }

    float px[APT], py[APT], pz[APT];      // optimal_traj pre-centering
    #pragma unroll
    for (int k = 0; k < APT; ++k) {
        const float t0x = c00*dx[k] + c01*dy[k] + c02*dz[k];
        const float t0y = c10*dx[k] + c11*dy[k] + c12*dz[k];
        const float t0z = c20*dx[k] + c21*dy[k] + c22*dz[k];

        float best = 3.4e38f;
        int   bo   = 0;
        #pragma unroll
        for (int a = 0; a < 3; ++a) {
            const float fa = (float)(a - 1);
            const float ex = t0x - fa*c00, ey = t0y - fa*c10, ez = t0z - fa*c20;
            #pragma unroll
            for (int b = 0; b < 3; ++b) {
                const float fb = (float)(b - 1);
                const float fx = ex - fb*c01, fy = ey - fb*c11, fz = ez - fb*c21;
                #pragma unroll
                for (int g = 0; g < 3; ++g) {
                    const float fg = (float)(g - 1);
                    const float gx = fx - fg*c02, gy = fy - fg*c12, gz = fz - fg*c22;
                    const float d2 = gx*gx + gy*gy + gz*gz;
                    const int o = a*9 + b*3 + g;
                    if (d2 < best) { best = d2; bo = o; }   // first-min == argmin
                }
            }
        }
        px[k] = dx[k] - (float)(bo/9 - 1);
        py[k] = dy[k] - (float)((bo/3)%3 - 1);
        pz[k] = dz[k] - (float)(bo%3 - 1);
    }

    // Per-structure mean over 64 atoms = 16 lanes x 4 atoms.
    float sx = px[0]+px[1]+px[2]+px[3];
    float sy = py[0]+py[1]+py[2]+py[3];
    float sz = pz[0]+pz[1]+pz[2]+pz[3];
    #pragma unroll
    for (int m = 8; m > 0; m >>= 1) {
        sx += __shfl_xor(sx, m);
        sy += __shfl_xor(sy, m);
        sz += __shfl_xor(sz, m);
    }
    const float inv = 1.0f / 64.0f;
    const float mx = sx*inv, my = sy*inv, mz = sz*inv;

    // L1 contribution over this thread's 4 atoms.
    const float J[12] = {ja.x,ja.y,ja.z,ja.w,jb.x,jb.y,jb.z,jb.w,jc.x,jc.y,jc.z,jc.w};
    float l = 0.0f;
    #pragma unroll
    for (int k = 0; k < APT; ++k) {
        l += fabsf(J[k*3+0] - (px[k]-mx))
           + fabsf(J[k*3+1] - (py[k]-my))
           + fabsf(J[k*3+2] - (pz[k]-mz));
    }

    // Wave reduce, then one scaled atomic per wave (4096 total, negligible
    // contention; fp32 rounding ~3e-5 << 7.9e-3 threshold).
    #pragma unroll
    for (int m = 32; m > 0; m >>= 1) l += __shfl_xor(l, m);
    if ((t & 63) == 0) atomicAdd(out, l * INV3N);
}

extern "C" void kernel_launch(void* const* d_in, const int* in_sizes, int n_in,
                              void* d_out, int out_size, void* d_ws, size_t ws_size,
                              hipStream_t stream) {
    const float* cell = (const float*)d_in[0];
    const float* x    = (const float*)d_in[1];
    const float* xt   = (const float*)d_in[2];
    const float* xtr  = (const float*)d_in[3];
    // d_in[4] = num_atoms: all 64, batch index hardcoded.

    float* out = (float*)d_out;

    otl_init<<<1, 64, 0, stream>>>(out);
    otl_main<<<GRID, BLOCK, 0, stream>>>(cell, x, xt, xtr, out);
}

// Round 6
// 13.382 us; speedup vs baseline: 4.9507x; 4.9507x over previous
//
#include <hip/hip_runtime.h>

// OptimalTrajLoss: B=16384 structures x 64 atoms, 27 periodic images.
// R6: R3's two-kernel structure (coop launch failed silently in R5; same-line
// atomics cost 57us in R4; fill nodes cost 40us in R2).
// Main-kernel math reformulated via Gram matrix:
//   d2(o) = d'Gd - 2*(Gd)'o + o'Go,  G = C'C
// Per-structure G(6) and q(o)=o'Go (27) precomputed in LDS; per-candidate
// cost drops ~249 -> ~130 lane-ops/atom. Argmin via packed key
// (d2 bits & ~63) | (a<<4|b<<2|g) + fminf tree (branchless, first-min ties).

static constexpr int BSTRUCT = 16384;
static constexpr int NATOMS  = BSTRUCT * 64;            // 1048576
static constexpr int BLOCK   = 256;
static constexpr int APT     = 4;                       // atoms per thread
static constexpr int GRID    = NATOMS / (BLOCK * APT);  // 1024
static constexpr int SPB     = 16;                      // structures per block

__global__ __launch_bounds__(BLOCK, 4) void otl_main(
    const float* __restrict__ cell,
    const float* __restrict__ x,
    const float* __restrict__ xt,
    const float* __restrict__ xtr,
    float* __restrict__ partial)
{
    const int t = threadIdx.x;

    __shared__ float cl[SPB * 9];
    __shared__ float sG[SPB][8];    // G11,G22,G33,G12,G13,G23 (+pad), 32B rows
    __shared__ float sQ[SPB][28];   // q(o) for o=a*9+b*3+g (+pad), 112B rows

    // Phase 0a: stage cells.
    if (t < SPB * 9) cl[t] = cell[blockIdx.x * (SPB * 9) + t];
    __syncthreads();

    // Phase 0b: G = C'C (6 unique entries per structure).
    if (t < SPB * 6) {
        const int s = t / 6, e = t - s * 6;
        const int i = (e < 3) ? e : ((e < 5) ? 0 : 1);
        const int j = (e < 3) ? e : ((e == 3) ? 1 : 2);
        const float* c = &cl[s * 9];
        sG[s][e] = c[i] * c[j] + c[3 + i] * c[3 + j] + c[6 + i] * c[6 + j];
    }
    __syncthreads();

    // Phase 0c: q(o) = o'Go table, 27 per structure.
    for (int u = t; u < SPB * 27; u += BLOCK) {
        const int s = u / 27, o = u - s * 27;
        const int a = o / 9, r = o - a * 9, b = r / 3, g = r - b * 3;
        const float f1 = (float)(a - 1), f2 = (float)(b - 1), f3 = (float)(g - 1);
        const float* G = sG[s];
        sQ[s][o] = G[0]*f1*f1 + G[1]*f2*f2 + G[2]*f3*f3
                 + 2.0f*(G[3]*f1*f2 + G[4]*f1*f3 + G[5]*f2*f3);
    }
    __syncthreads();

    const int sl = t >> 4;   // this thread's structure slot (16 lanes share)

    // G and q into registers (b128 LDS reads; broadcast within 16-lane group,
    // disjoint banks across the 4 groups of a wave for the 112B q rows).
    float G0,G1,G2,G3,G4,G5;
    {
        const float4 ga = reinterpret_cast<const float4*>(&sG[sl][0])[0];
        const float4 gb = reinterpret_cast<const float4*>(&sG[sl][0])[1];
        G0=ga.x; G1=ga.y; G2=ga.z; G3=ga.w; G4=gb.x; G5=gb.y;
    }
    float q[28];
    #pragma unroll
    for (int i = 0; i < 7; ++i)
        *reinterpret_cast<float4*>(&q[i*4]) =
            reinterpret_cast<const float4*>(&sQ[sl][0])[i];

    // 4 atoms = 12 floats = 3 float4 per array, coalesced dwordx4.
    const int f4 = (blockIdx.x * BLOCK + t) * 3;
    const float4 xa = reinterpret_cast<const float4*>(x)[f4 + 0];
    const float4 xb = reinterpret_cast<const float4*>(x)[f4 + 1];
    const float4 xc = reinterpret_cast<const float4*>(x)[f4 + 2];
    const float4 ta = reinterpret_cast<const float4*>(xt)[f4 + 0];
    const float4 tb = reinterpret_cast<const float4*>(xt)[f4 + 1];
    const float4 tc = reinterpret_cast<const float4*>(xt)[f4 + 2];

    float dxv[APT], dyv[APT], dzv[APT];   // x_tilde - x
    {
        const float X[12] = {xa.x,xa.y,xa.z,xa.w,xb.x,xb.y,xb.z,xb.w,xc.x,xc.y,xc.z,xc.w};
        const float T[12] = {ta.x,ta.y,ta.z,ta.w,tb.x,tb.y,tb.z,tb.w,tc.x,tc.y,tc.z,tc.w};
        #pragma unroll
        for (int k = 0; k < APT; ++k) {
            dxv[k] = T[k*3+0] - X[k*3+0];
            dyv[k] = T[k*3+1] - X[k*3+1];
            dzv[k] = T[k*3+2] - X[k*3+2];
        }
    }

    float px[APT], py[APT], pz[APT];
    #pragma unroll
    for (int k = 0; k < APT; ++k) {
        const float dx = dxv[k], dy = dyv[k], dz = dzv[k];
        // w = G d ; wd = d'Gd
        const float w1 = G0*dx + G3*dy + G4*dz;
        const float w2 = G3*dx + G1*dy + G5*dz;
        const float w3 = G4*dx + G5*dy + G2*dz;
        const float wd = w1*dx + w2*dy + w3*dz;
        const float tw1 = w1 + w1, tw2 = w2 + w2, tw3 = w3 + w3;

        // d2(o) = wd - 2w.o + q(o); staged scalar adds, packed-key min tree.
        float ka[3];
        #pragma unroll
        for (int a = 0; a < 3; ++a) {
            const float sa = (a == 0) ? wd + tw1 : (a == 1) ? wd : wd - tw1;
            float kb[3];
            #pragma unroll
            for (int b = 0; b < 3; ++b) {
                const float sb = (b == 0) ? sa + tw2 : (b == 1) ? sa : sa - tw2;
                const int qo = a*9 + b*3;
                const float d20 = (sb + tw3) + q[qo + 0];
                const float d21 =  sb        + q[qo + 1];
                const float d22 = (sb - tw3) + q[qo + 2];
                const unsigned base = (unsigned)((a << 4) | (b << 2));
                const unsigned k0 = (__float_as_uint(d20) & ~63u) | (base + 0u);
                const unsigned k1 = (__float_as_uint(d21) & ~63u) | (base + 1u);
                const unsigned k2 = (__float_as_uint(d22) & ~63u) | (base + 2u);
                kb[b] = fminf(fminf(__uint_as_float(k0), __uint_as_float(k1)),
                              __uint_as_float(k2));
            }
            ka[a] = fminf(fminf(kb[0], kb[1]), kb[2]);
        }
        const float best = fminf(fminf(ka[0], ka[1]), ka[2]);
        const unsigned bo = __float_as_uint(best) & 63u;
        px[k] = dx - (float)((int)(bo >> 4)        - 1);
        py[k] = dy - (float)((int)((bo >> 2) & 3u) - 1);
        pz[k] = dz - (float)((int)(bo & 3u)        - 1);
    }

    // Per-structure mean over 64 atoms = 16 lanes x 4 atoms.
    float sx = px[0]+px[1]+px[2]+px[3];
    float sy = py[0]+py[1]+py[2]+py[3];
    float sz = pz[0]+pz[1]+pz[2]+pz[3];
    #pragma unroll
    for (int m = 8; m > 0; m >>= 1) {
        sx += __shfl_xor(sx, m);
        sy += __shfl_xor(sy, m);
        sz += __shfl_xor(sz, m);
    }
    const float inv = 1.0f / 64.0f;
    const float mx = sx*inv, my = sy*inv, mz = sz*inv;

    // L1 contribution over this thread's 4 atoms.
    const float4 ja = reinterpret_cast<const float4*>(xtr)[f4 + 0];
    const float4 jb = reinterpret_cast<const float4*>(xtr)[f4 + 1];
    const float4 jc = reinterpret_cast<const float4*>(xtr)[f4 + 2];
    const float J[12] = {ja.x,ja.y,ja.z,ja.w,jb.x,jb.y,jb.z,jb.w,jc.x,jc.y,jc.z,jc.w};
    float l = 0.0f;
    #pragma unroll
    for (int k = 0; k < APT; ++k) {
        l += fabsf(J[k*3+0] - (px[k]-mx))
           + fabsf(J[k*3+1] - (py[k]-my))
           + fabsf(J[k*3+2] - (pz[k]-mz));
    }

    // Wave reduce, cross-wave via LDS, plain store (no atomics).
    #pragma unroll
    for (int m = 32; m > 0; m >>= 1) l += __shfl_xor(l, m);

    __shared__ float ls[BLOCK / 64];
    const int lane = t & 63, wave = t >> 6;
    if (lane == 0) ls[wave] = l;
    __syncthreads();
    if (t == 0)
        partial[blockIdx.x] = ls[0] + ls[1] + ls[2] + ls[3];
}

__global__ __launch_bounds__(BLOCK) void otl_reduce(
    const float* __restrict__ partial, float* __restrict__ out)
{
    const int t = threadIdx.x;
    const float4 p = reinterpret_cast<const float4*>(partial)[t];  // 256*4 = 1024
    double acc = (double)p.x + (double)p.y + (double)p.z + (double)p.w;
    #pragma unroll
    for (int m = 32; m > 0; m >>= 1)
        acc += __shfl_xor(acc, m);
    __shared__ double ds[BLOCK / 64];
    const int lane = t & 63, wave = t >> 6;
    if (lane == 0) ds[wave] = acc;
    __syncthreads();
    if (t == 0) {
        const double s = ds[0] + ds[1] + ds[2] + ds[3];
        out[0] = (float)(s / (3.0 * (double)NATOMS));
    }
}

extern "C" void kernel_launch(void* const* d_in, const int* in_sizes, int n_in,
                              void* d_out, int out_size, void* d_ws, size_t ws_size,
                              hipStream_t stream) {
    const float* cell = (const float*)d_in[0];
    const float* x    = (const float*)d_in[1];
    const float* xt   = (const float*)d_in[2];
    const float* xtr  = (const float*)d_in[3];
    // d_in[4] = num_atoms: all 64, batch index hardcoded.

    float* partials = (float*)d_ws;   // 1024 floats, fully rewritten each call
    float* out      = (float*)d_out;

    otl_main<<<GRID, BLOCK, 0, stream>>>(cell, x, xt, xtr, partials);
    otl_reduce<<<1, BLOCK, 0, stream>>>(partials, out);
}